// Round 6
// baseline (118.509 us; speedup 1.0000x reference)
//
#include <hip/hip_runtime.h>
#include <math.h>

#define NB   2
#define CIN  128
#define CH   64
#define NPOS 4096

typedef __attribute__((ext_vector_type(8))) short s16x8;   // 8 bf16 (4 VGPRs)
typedef __attribute__((ext_vector_type(4))) float f32x4;

__device__ __forceinline__ unsigned int bfrne(float f) {
    unsigned int u = __float_as_uint(f);
    return (u + 0x7FFFu + ((u >> 16) & 1u)) >> 16;
}
__device__ __forceinline__ unsigned int pk_rne(float lo, float hi) {
    return bfrne(lo) | (bfrne(hi) << 16);
}
// fast half-up pack for non-negative values (exp outputs)
__device__ __forceinline__ unsigned int pk_fast(float lo, float hi) {
    unsigned int a = (__float_as_uint(lo) + 0x8000u) >> 16;
    unsigned int b = (__float_as_uint(hi) + 0x8000u) & 0xFFFF0000u;
    return a | b;
}
__device__ __forceinline__ float bf2f(unsigned short h) {
    return __uint_as_float(((unsigned int)h) << 16);
}

// ---------------------------------------------------------------------------
// Kernel 0: pack all weights to bf16 once.  Wb: [Wq|Wk|Wv|Wpost], 8192 each.
// ---------------------------------------------------------------------------
__global__ __launch_bounds__(256) void packw_kernel(
    const float* __restrict__ Wq, const float* __restrict__ Wk,
    const float* __restrict__ Wv, const float* __restrict__ Wpost,
    unsigned short* __restrict__ Wb)
{
    const int gid = blockIdx.x * 256 + threadIdx.x;   // 8192 threads
    const int base = gid * 4;
    const int mat = base >> 13, off = base & 8191;
    const float* src = (mat == 0) ? Wq : (mat == 1) ? Wk : (mat == 2) ? Wv : Wpost;
    float4 f = *(const float4*)&src[off];
    uint2 st = make_uint2(pk_rne(f.x, f.y), pk_rne(f.z, f.w));
    *(uint2*)&Wb[mat * 8192 + off] = st;
}

// ---------------------------------------------------------------------------
// Kernel 1: q/k/v projections via MFMA.  Grid (256 p-tiles, 3 o-groups, b)
// = 1536 blocks (~6/CU).  Each wave does ONE 16-o tile (tile = og*4 + w).
// x staged+transposed in LDS; B = x split hi+lo bf16 (fp32-x accuracy);
// A = pre-packed bf16 W.   kT,qT: (b,pos,c) bf16;  v32: (b,c,pos) fp32.
// ---------------------------------------------------------------------------
#define XTS 132
__global__ __launch_bounds__(256, 4) void qkv_kernel(
    const float* __restrict__ x, const unsigned short* __restrict__ Wb,
    unsigned short* __restrict__ kT, unsigned short* __restrict__ qT,
    float* __restrict__ v32)
{
    __shared__ __align__(16) float xT[16 * XTS];   // 8.25 KB
    const int b  = blockIdx.z;
    const int og = blockIdx.y;
    const int p0 = blockIdx.x * 16;
    const int tid = threadIdx.x;

    #pragma unroll
    for (int it = 0; it < 2; ++it) {
        int idx = it * 256 + tid;                  // 0..511
        int c = idx >> 2, p4 = (idx & 3) * 4;
        float4 g = *(const float4*)&x[((size_t)b * CIN + c) * NPOS + p0 + p4];
        xT[(p4 + 0) * XTS + c] = g.x;
        xT[(p4 + 1) * XTS + c] = g.y;
        xT[(p4 + 2) * XTS + c] = g.z;
        xT[(p4 + 3) * XTS + c] = g.w;
    }
    __syncthreads();

    const int w = tid >> 6, l = tid & 63, lm = l & 15, lq = l >> 4;
    const int p = p0 + lm;

    s16x8 Bhi[4], Blo[4];
    #pragma unroll
    for (int ck = 0; ck < 4; ++ck) {
        const float* xr = &xT[lm * XTS + ck * 32 + lq * 8];
        union { unsigned int u[4]; s16x8 v; } chv, clv;
        #pragma unroll
        for (int j = 0; j < 4; ++j) {
            float x0 = xr[2 * j], x1 = xr[2 * j + 1];
            unsigned int h0 = bfrne(x0), h1 = bfrne(x1);
            chv.u[j] = h0 | (h1 << 16);
            clv.u[j] = pk_rne(x0 - __uint_as_float(h0 << 16),
                              x1 - __uint_as_float(h1 << 16));
        }
        Bhi[ck] = chv.v; Blo[ck] = clv.v;
    }

    const int tile = og * 4 + w;                   // 0..11
    const int mat = tile >> 2, o0 = (tile & 3) * 16;
    const unsigned short* Wm = Wb + mat * 8192;
    f32x4 acc = {0.f, 0.f, 0.f, 0.f};
    #pragma unroll
    for (int ck = 0; ck < 4; ++ck) {
        s16x8 aW = *(const s16x8*)&Wm[(o0 + lm) * CIN + ck * 32 + lq * 8];
        acc = __builtin_amdgcn_mfma_f32_16x16x32_bf16(aW, Bhi[ck], acc, 0,0,0);
        acc = __builtin_amdgcn_mfma_f32_16x16x32_bf16(aW, Blo[ck], acc, 0,0,0);
    }
    if (mat < 2) {
        unsigned short* dst = (mat == 0) ? qT : kT;
        uint2 st = make_uint2(pk_rne(acc[0], acc[1]), pk_rne(acc[2], acc[3]));
        *(uint2*)&dst[((size_t)b * NPOS + p) * CH + o0 + lq * 4] = st;
    } else {
        #pragma unroll
        for (int r = 0; r < 4; ++r)
            v32[((size_t)b * CH + o0 + lq * 4 + r) * NPOS + p] = acc[r];
    }
}

// ---------------------------------------------------------------------------
// Kernel 2: softmax denominator partials over j-EIGHTHS.  Grid (64 i-tiles,
// 8 jq, b) = 1024 blocks (4/CU).  Block = 64 i; wave w owns i-sub w*16
// (A-frags reg-resident, no cross-wave reduce).  q staged per 64-j tile in
// frag-ordered LDS, DOUBLE-BUFFERED -> 1 barrier/iter, 8 iters.
// ---------------------------------------------------------------------------
__global__ __launch_bounds__(256, 4) void stats_kernel(
    const unsigned short* __restrict__ kT,
    const unsigned short* __restrict__ qT,
    float* __restrict__ lpart)
{
    __shared__ __align__(16) unsigned short qbuf[2][4096];   // 16 KB
    const int b  = blockIdx.z;
    const int jq = blockIdx.y;
    const int i0 = blockIdx.x * 64;
    const int tid = threadIdx.x;
    const int w = tid >> 6, l = tid & 63, lm = l & 15, lq = l >> 4;

    s16x8 a0 = *(const s16x8*)&kT[
        ((size_t)b * NPOS + i0 + w * 16 + lm) * CH + lq * 8];
    s16x8 a1 = *(const s16x8*)&kT[
        ((size_t)b * NPOS + i0 + w * 16 + lm) * CH + 32 + lq * 8];

    // wave w stages frag-blocks {2w, 2w+1}: j-subtile w, kc = 0/1
    const unsigned short* qpt =
        qT + ((size_t)b * NPOS + jq * 512 + w * 16 + lm) * CH + lq * 8;
    s16x8 st0 = *(const s16x8*)(qpt);
    s16x8 st1 = *(const s16x8*)(qpt + 32);

    float rs[4] = {0.f, 0.f, 0.f, 0.f};
    for (int t = 0; t < 8; ++t) {
        const int buf = t & 1;
        *(s16x8*)&qbuf[buf][(2 * w + 0) * 512 + l * 8] = st0;
        *(s16x8*)&qbuf[buf][(2 * w + 1) * 512 + l * 8] = st1;
        if (t < 7) {
            const unsigned short* qn = qpt + (size_t)(t + 1) * 64 * CH;
            st0 = *(const s16x8*)(qn);
            st1 = *(const s16x8*)(qn + 32);
        }
        __syncthreads();
        #pragma unroll
        for (int js = 0; js < 4; ++js) {
            s16x8 b0 = *(const s16x8*)&qbuf[buf][(js * 2 + 0) * 512 + l * 8];
            s16x8 b1 = *(const s16x8*)&qbuf[buf][(js * 2 + 1) * 512 + l * 8];
            f32x4 sc = {0.f, 0.f, 0.f, 0.f};
            sc = __builtin_amdgcn_mfma_f32_16x16x32_bf16(a0, b0, sc, 0,0,0);
            sc = __builtin_amdgcn_mfma_f32_16x16x32_bf16(a1, b1, sc, 0,0,0);
            rs[0] += __expf(sc[0]); rs[1] += __expf(sc[1]);
            rs[2] += __expf(sc[2]); rs[3] += __expf(sc[3]);
        }
        // next iter stores into the OTHER buffer -> single barrier is safe
    }

    #pragma unroll
    for (int r = 0; r < 4; ++r) {
        rs[r] += __shfl_xor(rs[r], 1);
        rs[r] += __shfl_xor(rs[r], 2);
        rs[r] += __shfl_xor(rs[r], 4);
        rs[r] += __shfl_xor(rs[r], 8);
    }
    if (lm == 0) {
        #pragma unroll
        for (int r = 0; r < 4; ++r)
            lpart[(size_t)jq * NB * NPOS + b * NPOS
                  + i0 + w * 16 + lq * 4 + r] = rs[r];
    }
}

// ---------------------------------------------------------------------------
// Kernel 3: combine 8 partial denominators and prescale v:
//   vbs[c,i] = bf16( v32[c,i] / (sum_q lpart[q][i]) )
// ---------------------------------------------------------------------------
__global__ __launch_bounds__(256) void combine_kernel(
    const float* __restrict__ lpart, const float* __restrict__ v32,
    unsigned short* __restrict__ vbs)
{
    const int idx4 = blockIdx.x * 256 + threadIdx.x;
    const int base = idx4 * 4;                 // flat (b,c,i)
    const int b = base >> 18;
    const int i = base & (NPOS - 1);
    const float* lp = lpart + b * NPOS + i;
    float sx = 0.f, sy = 0.f, sz = 0.f, sw = 0.f;
    #pragma unroll
    for (int qq = 0; qq < 8; ++qq) {
        float4 lv = *(const float4*)(lp + (size_t)qq * NB * NPOS);
        sx += lv.x; sy += lv.y; sz += lv.z; sw += lv.w;
    }
    float4 v = *(const float4*)&v32[base];
    uint2 st = make_uint2(pk_rne(v.x / sx, v.y / sy),
                          pk_rne(v.z / sz, v.w / sw));
    *(uint2*)&vbs[base] = st;
}

// ---------------------------------------------------------------------------
// Kernel 4: aggregation over i-SIXTEENTHS.  Grid (32 j-tiles, 16 iq, b)
// = 1024 blocks (4/CU).  U[iq][b][j][c] bf16 partials.  Wave owns 32 j
// (q-frags reg-resident, 64c x 32j accumulator).  Per 32-i iter: k/v tiles
// in frag-ordered LDS, DOUBLE-BUFFERED -> 1 barrier/iter, 8 iters.
// 8 score MFMAs -> exp -> bpermute C->B transpose -> 8 PV MFMAs.
// ---------------------------------------------------------------------------
__global__ __launch_bounds__(256, 4) void agg_kernel(
    const unsigned short* __restrict__ kT,
    const unsigned short* __restrict__ qT,
    const unsigned short* __restrict__ vbs,
    unsigned short* __restrict__ U)
{
    __shared__ __align__(16) unsigned short kbuf[2][2048];   // 8 KB
    __shared__ __align__(16) unsigned short vbuf[2][2048];   // 8 KB
    const int b  = blockIdx.z;
    const int iq = blockIdx.y;
    const int j0 = blockIdx.x * 128;
    const int tid = threadIdx.x;
    const int w = tid >> 6, l = tid & 63, lm = l & 15, lq = l >> 4;

    s16x8 qb[2][2];
    #pragma unroll
    for (int js = 0; js < 2; ++js)
        #pragma unroll
        for (int kc = 0; kc < 2; ++kc)
            qb[js][kc] = *(const s16x8*)&qT[
                ((size_t)b * NPOS + j0 + w * 32 + js * 16 + lm) * CH + kc * 32 + lq * 8];

    int addr[4];
    #pragma unroll
    for (int d = 0; d < 4; ++d)
        addr[d] = (lm + 16 * (2 * (lq & 1) + (d >> 1))) << 2;
    const bool lowhalf = (lq < 2);

    const unsigned short* kpt = kT
        + ((size_t)b * NPOS + iq * 256 + (w >> 1) * 16 + lm) * CH
        + (w & 1) * 32 + lq * 8;
    const unsigned short* vpt = vbs
        + ((size_t)b * CH + w * 16 + lm) * NPOS + iq * 256 + lq * 8;

    f32x4 acc[2][4] = {};
    s16x8 kst = *(const s16x8*)kpt;
    s16x8 vst = *(const s16x8*)vpt;

    for (int t = 0; t < 8; ++t) {
        const int buf = t & 1;
        *(s16x8*)&kbuf[buf][w * 512 + l * 8] = kst;
        *(s16x8*)&vbuf[buf][w * 512 + l * 8] = vst;
        if (t < 7) {
            kst = *(const s16x8*)(kpt + (t + 1) * 32 * CH);
            vst = *(const s16x8*)(vpt + (t + 1) * 32);
        }
        __syncthreads();

        s16x8 kA[2][2], vA[4];
        #pragma unroll
        for (int s = 0; s < 2; ++s)
            #pragma unroll
            for (int kc = 0; kc < 2; ++kc)
                kA[s][kc] = *(const s16x8*)&kbuf[buf][(s * 2 + kc) * 512 + l * 8];
        #pragma unroll
        for (int cs = 0; cs < 4; ++cs)
            vA[cs] = *(const s16x8*)&vbuf[buf][cs * 512 + l * 8];

        #pragma unroll
        for (int js = 0; js < 2; ++js) {
            f32x4 s0 = {0,0,0,0}, s1 = {0,0,0,0};
            s0 = __builtin_amdgcn_mfma_f32_16x16x32_bf16(kA[0][0], qb[js][0], s0, 0,0,0);
            s0 = __builtin_amdgcn_mfma_f32_16x16x32_bf16(kA[0][1], qb[js][1], s0, 0,0,0);
            s1 = __builtin_amdgcn_mfma_f32_16x16x32_bf16(kA[1][0], qb[js][0], s1, 0,0,0);
            s1 = __builtin_amdgcn_mfma_f32_16x16x32_bf16(kA[1][1], qb[js][1], s1, 0,0,0);

            unsigned int P0[2], P1[2];
            P0[0] = pk_fast(__expf(s0[0]), __expf(s0[1]));
            P0[1] = pk_fast(__expf(s0[2]), __expf(s0[3]));
            P1[0] = pk_fast(__expf(s1[0]), __expf(s1[1]));
            P1[1] = pk_fast(__expf(s1[2]), __expf(s1[3]));

            union { unsigned int u[4]; s16x8 v; } B;
            #pragma unroll
            for (int d = 0; d < 4; ++d) {
                int t0 = __builtin_amdgcn_ds_bpermute(addr[d], (int)P0[d & 1]);
                int t1 = __builtin_amdgcn_ds_bpermute(addr[d], (int)P1[d & 1]);
                B.u[d] = lowhalf ? (unsigned int)t0 : (unsigned int)t1;
            }
            #pragma unroll
            for (int cs = 0; cs < 4; ++cs)
                acc[js][cs] = __builtin_amdgcn_mfma_f32_16x16x32_bf16(
                    vA[cs], B.v, acc[js][cs], 0,0,0);
        }
        // next iter writes the OTHER buffer -> single barrier is safe
    }

    unsigned short* Up = U + ((size_t)iq * NB + b) * NPOS * CH;
    #pragma unroll
    for (int js = 0; js < 2; ++js)
        #pragma unroll
        for (int cs = 0; cs < 4; ++cs) {
            uint2 st = make_uint2(pk_rne(acc[js][cs][0], acc[js][cs][1]),
                                  pk_rne(acc[js][cs][2], acc[js][cs][3]));
            *(uint2*)&Up[(size_t)(j0 + w * 32 + js * 16 + lm) * CH
                         + cs * 16 + lq * 4] = st;
        }
}

// ---------------------------------------------------------------------------
// Kernel 5: post projection + residual.  Grid (256 p-tiles, b) = 512 blocks.
// Block = 16 pos; wave w does o-tiles {2w, 2w+1}.  B = sum of 16 bf16 U
// partials (fp32 accumulate), A = pre-packed Wpost bf16, + x residual.
// ---------------------------------------------------------------------------
__global__ __launch_bounds__(256, 4) void post_kernel(
    const float* __restrict__ x, const unsigned short* __restrict__ Wb,
    const unsigned short* __restrict__ U, float* __restrict__ out)
{
    const int b  = blockIdx.y;
    const int p0 = blockIdx.x * 16;
    const int tid = threadIdx.x;
    const int w = tid >> 6, l = tid & 63, lm = l & 15, lq = l >> 4;
    const int p = p0 + lm;
    const size_t PS = (size_t)NB * NPOS * CH;

    const unsigned short* u = U + ((size_t)b * NPOS + p) * CH;
    const unsigned short* Wpb = Wb + 3 * 8192;
    s16x8 Bf[2];
    #pragma unroll
    for (int ck = 0; ck < 2; ++ck) {
        float sv[8] = {};
        #pragma unroll
        for (int qq = 0; qq < 16; ++qq) {
            union { s16x8 v; unsigned short us[8]; } uu;
            uu.v = *(const s16x8*)(u + (size_t)qq * PS + ck * 32 + lq * 8);
            #pragma unroll
            for (int j = 0; j < 8; ++j) sv[j] += bf2f(uu.us[j]);
        }
        union { unsigned int u[4]; s16x8 v; } cb;
        #pragma unroll
        for (int j = 0; j < 4; ++j) cb.u[j] = pk_rne(sv[2*j], sv[2*j+1]);
        Bf[ck] = cb.v;
    }

    #pragma unroll
    for (int ot = 0; ot < 2; ++ot) {
        const int o0 = (w * 2 + ot) * 16;
        f32x4 acc = {0.f, 0.f, 0.f, 0.f};
        #pragma unroll
        for (int ck = 0; ck < 2; ++ck) {
            s16x8 aW = *(const s16x8*)&Wpb[(o0 + lm) * CH + ck * 32 + lq * 8];
            acc = __builtin_amdgcn_mfma_f32_16x16x32_bf16(aW, Bf[ck], acc, 0,0,0);
        }
        #pragma unroll
        for (int r = 0; r < 4; ++r) {
            size_t gi = ((size_t)b * CIN + o0 + lq * 4 + r) * NPOS + p;
            out[gi] = x[gi] + acc[r];
        }
    }
}

extern "C" void kernel_launch(void* const* d_in, const int* in_sizes, int n_in,
                              void* d_out, int out_size, void* d_ws, size_t ws_size,
                              hipStream_t stream) {
    const float* x     = (const float*)d_in[0];
    const float* Wq    = (const float*)d_in[1];
    const float* Wk    = (const float*)d_in[2];
    const float* Wv    = (const float*)d_in[3];
    const float* Wpost = (const float*)d_in[4];
    float* out = (float*)d_out;

    // ws: kT(1MB) qT(1MB) vbs(1MB) Wb(64KB) lpart(256KB) U(16MB bf16, 16
    // partials; start of U doubles as v32 fp32, consumed before agg writes)
    unsigned short* kT  = (unsigned short*)d_ws;
    unsigned short* qT  = kT + (size_t)NB * NPOS * CH;
    unsigned short* vbs = qT + (size_t)NB * NPOS * CH;
    unsigned short* Wb  = vbs + (size_t)NB * NPOS * CH;
    float* lpart = (float*)(Wb + 4 * 8192);
    unsigned short* U = (unsigned short*)(lpart + (size_t)8 * NB * NPOS);
    float* v32 = (float*)U;   // overlay

    packw_kernel  <<<dim3(32), 256, 0, stream>>>(Wq, Wk, Wv, Wpost, Wb);
    qkv_kernel    <<<dim3(NPOS / 16, 3, NB), 256, 0, stream>>>(x, Wb, kT, qT, v32);
    stats_kernel  <<<dim3(NPOS / 64, 8, NB), 256, 0, stream>>>(kT, qT, lpart);
    combine_kernel<<<dim3(NB * CH * NPOS / 1024), 256, 0, stream>>>(lpart, v32, vbs);
    agg_kernel    <<<dim3(NPOS / 128, 16, NB), 256, 0, stream>>>(kT, qT, vbs, U);
    post_kernel   <<<dim3(NPOS / 16, NB), 256, 0, stream>>>(x, Wb, U, out);
}

// Round 7
// 107.665 us; speedup vs baseline: 1.1007x; 1.1007x over previous
//
#include <hip/hip_runtime.h>
#include <math.h>

#define NB   2
#define CIN  128
#define CH   64
#define NPOS 4096

typedef __attribute__((ext_vector_type(8))) short s16x8;   // 8 bf16 (4 VGPRs)
typedef __attribute__((ext_vector_type(4))) float f32x4;

__device__ __forceinline__ unsigned int bfrne(float f) {
    unsigned int u = __float_as_uint(f);
    return (u + 0x7FFFu + ((u >> 16) & 1u)) >> 16;
}
__device__ __forceinline__ unsigned int pk_rne(float lo, float hi) {
    return bfrne(lo) | (bfrne(hi) << 16);
}
// fast half-up pack for non-negative values (exp outputs)
__device__ __forceinline__ unsigned int pk_fast(float lo, float hi) {
    unsigned int a = (__float_as_uint(lo) + 0x8000u) >> 16;
    unsigned int b = (__float_as_uint(hi) + 0x8000u) & 0xFFFF0000u;
    return a | b;
}
__device__ __forceinline__ float bf2f(unsigned short h) {
    return __uint_as_float(((unsigned int)h) << 16);
}

// ---------------------------------------------------------------------------
// Kernel 0: pack all weights to bf16 once.  Wb: [Wq|Wk|Wv|Wpost], 8192 each.
// ---------------------------------------------------------------------------
__global__ __launch_bounds__(256) void packw_kernel(
    const float* __restrict__ Wq, const float* __restrict__ Wk,
    const float* __restrict__ Wv, const float* __restrict__ Wpost,
    unsigned short* __restrict__ Wb)
{
    const int gid = blockIdx.x * 256 + threadIdx.x;   // 8192 threads
    const int base = gid * 4;
    const int mat = base >> 13, off = base & 8191;
    const float* src = (mat == 0) ? Wq : (mat == 1) ? Wk : (mat == 2) ? Wv : Wpost;
    float4 f = *(const float4*)&src[off];
    uint2 st = make_uint2(pk_rne(f.x, f.y), pk_rne(f.z, f.w));
    *(uint2*)&Wb[mat * 8192 + off] = st;
}

// ---------------------------------------------------------------------------
// Kernel 1: q/k/v projections via MFMA.  16-pos tiles -> 512 blocks (2/CU).
// x staged+transposed in LDS (once); B = x split hi+lo bf16; A = packed W.
// Each wave: 3 of 12 o-tiles.  kT,qT: (b,pos,c) bf16; vbs: (b,c,pos) bf16.
// ---------------------------------------------------------------------------
#define XTS 132
__global__ __launch_bounds__(256) void qkv_kernel(
    const float* __restrict__ x, const unsigned short* __restrict__ Wb,
    unsigned short* __restrict__ kT, unsigned short* __restrict__ qT,
    unsigned short* __restrict__ vbs)
{
    __shared__ __align__(16) float xT[16 * XTS];   // 8.25 KB
    const int b  = blockIdx.y;
    const int p0 = blockIdx.x * 16;
    const int tid = threadIdx.x;

    #pragma unroll
    for (int it = 0; it < 2; ++it) {
        int idx = it * 256 + tid;                  // 0..511
        int c = idx >> 2, p4 = (idx & 3) * 4;
        float4 g = *(const float4*)&x[((size_t)b * CIN + c) * NPOS + p0 + p4];
        xT[(p4 + 0) * XTS + c] = g.x;
        xT[(p4 + 1) * XTS + c] = g.y;
        xT[(p4 + 2) * XTS + c] = g.z;
        xT[(p4 + 3) * XTS + c] = g.w;
    }
    __syncthreads();

    const int w = tid >> 6, l = tid & 63, lm = l & 15, lq = l >> 4;
    const int p = p0 + lm;

    s16x8 Bhi[4], Blo[4];
    #pragma unroll
    for (int ck = 0; ck < 4; ++ck) {
        const float* xr = &xT[lm * XTS + ck * 32 + lq * 8];
        union { unsigned int u[4]; s16x8 v; } chv, clv;
        #pragma unroll
        for (int j = 0; j < 4; ++j) {
            float x0 = xr[2 * j], x1 = xr[2 * j + 1];
            unsigned int h0 = bfrne(x0), h1 = bfrne(x1);
            chv.u[j] = h0 | (h1 << 16);
            clv.u[j] = pk_rne(x0 - __uint_as_float(h0 << 16),
                              x1 - __uint_as_float(h1 << 16));
        }
        Bhi[ck] = chv.v; Blo[ck] = clv.v;
    }

    #pragma unroll
    for (int t3 = 0; t3 < 3; ++t3) {
        const int tile = w * 3 + t3;
        const int mat = tile >> 2, o0 = (tile & 3) * 16;
        const unsigned short* Wm = Wb + mat * 8192;
        f32x4 acc = {0.f, 0.f, 0.f, 0.f};
        #pragma unroll
        for (int ck = 0; ck < 4; ++ck) {
            s16x8 aW = *(const s16x8*)&Wm[(o0 + lm) * CIN + ck * 32 + lq * 8];
            acc = __builtin_amdgcn_mfma_f32_16x16x32_bf16(aW, Bhi[ck], acc, 0,0,0);
            acc = __builtin_amdgcn_mfma_f32_16x16x32_bf16(aW, Blo[ck], acc, 0,0,0);
        }
        if (mat < 2) {
            unsigned short* dst = (mat == 0) ? qT : kT;
            uint2 st = make_uint2(pk_rne(acc[0], acc[1]), pk_rne(acc[2], acc[3]));
            *(uint2*)&dst[((size_t)b * NPOS + p) * CH + o0 + lq * 4] = st;
        } else {
            #pragma unroll
            for (int r = 0; r < 4; ++r)
                vbs[((size_t)b * CH + o0 + lq * 4 + r) * NPOS + p] =
                    (unsigned short)bfrne(acc[r]);
        }
    }
}

// ---------------------------------------------------------------------------
// Kernel 2: softmax denominator partials over j-EIGHTHS.  Grid (64 i-tiles,
// 8 jq, b) = 1024 blocks (4/CU).  Wave w owns 16 i (A-frags reg-resident,
// no cross-wave reduce).  q staged per 64-j tile in frag-ordered LDS,
// double-buffered -> 1 barrier/iter, 8 iters.
// ---------------------------------------------------------------------------
__global__ __launch_bounds__(256, 4) void stats_kernel(
    const unsigned short* __restrict__ kT,
    const unsigned short* __restrict__ qT,
    float* __restrict__ lpart)
{
    __shared__ __align__(16) unsigned short qbuf[2][4096];   // 16 KB
    const int b  = blockIdx.z;
    const int jq = blockIdx.y;
    const int i0 = blockIdx.x * 64;
    const int tid = threadIdx.x;
    const int w = tid >> 6, l = tid & 63, lm = l & 15, lq = l >> 4;

    s16x8 a0 = *(const s16x8*)&kT[
        ((size_t)b * NPOS + i0 + w * 16 + lm) * CH + lq * 8];
    s16x8 a1 = *(const s16x8*)&kT[
        ((size_t)b * NPOS + i0 + w * 16 + lm) * CH + 32 + lq * 8];

    const unsigned short* qpt =
        qT + ((size_t)b * NPOS + jq * 512 + w * 16 + lm) * CH + lq * 8;
    s16x8 st0 = *(const s16x8*)(qpt);
    s16x8 st1 = *(const s16x8*)(qpt + 32);

    float rs[4] = {0.f, 0.f, 0.f, 0.f};
    for (int t = 0; t < 8; ++t) {
        const int buf = t & 1;
        *(s16x8*)&qbuf[buf][(2 * w + 0) * 512 + l * 8] = st0;
        *(s16x8*)&qbuf[buf][(2 * w + 1) * 512 + l * 8] = st1;
        if (t < 7) {
            const unsigned short* qn = qpt + (size_t)(t + 1) * 64 * CH;
            st0 = *(const s16x8*)(qn);
            st1 = *(const s16x8*)(qn + 32);
        }
        __syncthreads();
        #pragma unroll
        for (int js = 0; js < 4; ++js) {
            s16x8 b0 = *(const s16x8*)&qbuf[buf][(js * 2 + 0) * 512 + l * 8];
            s16x8 b1 = *(const s16x8*)&qbuf[buf][(js * 2 + 1) * 512 + l * 8];
            f32x4 sc = {0.f, 0.f, 0.f, 0.f};
            sc = __builtin_amdgcn_mfma_f32_16x16x32_bf16(a0, b0, sc, 0,0,0);
            sc = __builtin_amdgcn_mfma_f32_16x16x32_bf16(a1, b1, sc, 0,0,0);
            rs[0] += __expf(sc[0]); rs[1] += __expf(sc[1]);
            rs[2] += __expf(sc[2]); rs[3] += __expf(sc[3]);
        }
    }

    #pragma unroll
    for (int r = 0; r < 4; ++r) {
        rs[r] += __shfl_xor(rs[r], 1);
        rs[r] += __shfl_xor(rs[r], 2);
        rs[r] += __shfl_xor(rs[r], 4);
        rs[r] += __shfl_xor(rs[r], 8);
    }
    if (lm == 0) {
        #pragma unroll
        for (int r = 0; r < 4; ++r)
            lpart[(size_t)jq * NB * NPOS + b * NPOS
                  + i0 + w * 16 + lq * 4 + r] = rs[r];
    }
}

// ---------------------------------------------------------------------------
// Kernel 3: gl[i] = 1 / sum_q lpart[q][i]   (tiny; 8 blocks)
// ---------------------------------------------------------------------------
__global__ __launch_bounds__(256) void gl_kernel(
    const float* __restrict__ lpart, float* __restrict__ gl)
{
    const int idx4 = blockIdx.x * 256 + threadIdx.x;   // 2048 threads
    const int base = idx4 * 4;                         // flat (b,i)
    float sx = 0.f, sy = 0.f, sz = 0.f, sw = 0.f;
    #pragma unroll
    for (int qq = 0; qq < 8; ++qq) {
        float4 lv = *(const float4*)(lpart + (size_t)qq * NB * NPOS + base);
        sx += lv.x; sy += lv.y; sz += lv.z; sw += lv.w;
    }
    float4 o = make_float4(1.f / sx, 1.f / sy, 1.f / sz, 1.f / sw);
    *(float4*)&gl[base] = o;
}

// ---------------------------------------------------------------------------
// Kernel 4: aggregation over i-EIGHTHS.  Grid (32 j-tiles, 8 iq, b) = 512
// blocks.  U[iq][b][j][c] bf16 partials.  Wave owns 32 j (q-frags
// reg-resident, 64c x 32j accumulator).  rl (=1/l) folded into the exp
// weight pack (rls staged in LDS).  Per 32-i iter: k/v frag-ordered LDS,
// double-buffered -> 1 barrier/iter, 16 iters.  8 score MFMAs -> exp*rl ->
// bpermute C->B transpose -> 8 PV MFMAs.
// ---------------------------------------------------------------------------
__global__ __launch_bounds__(256, 4) void agg_kernel(
    const unsigned short* __restrict__ kT,
    const unsigned short* __restrict__ qT,
    const unsigned short* __restrict__ vbs,
    const float* __restrict__ gl,
    unsigned short* __restrict__ U)
{
    __shared__ __align__(16) unsigned short kbuf[2][2048];   // 8 KB
    __shared__ __align__(16) unsigned short vbuf[2][2048];   // 8 KB
    __shared__ __align__(16) float rls[512];                 // 2 KB
    const int b  = blockIdx.z;
    const int iq = blockIdx.y;
    const int j0 = blockIdx.x * 128;
    const int tid = threadIdx.x;
    const int w = tid >> 6, l = tid & 63, lm = l & 15, lq = l >> 4;

    // stage rl for this block's 512-i slice
    *(float2*)&rls[tid * 2] =
        *(const float2*)&gl[(size_t)b * NPOS + iq * 512 + tid * 2];

    s16x8 qb[2][2];
    #pragma unroll
    for (int js = 0; js < 2; ++js)
        #pragma unroll
        for (int kc = 0; kc < 2; ++kc)
            qb[js][kc] = *(const s16x8*)&qT[
                ((size_t)b * NPOS + j0 + w * 32 + js * 16 + lm) * CH + kc * 32 + lq * 8];

    int addr[4];
    #pragma unroll
    for (int d = 0; d < 4; ++d)
        addr[d] = (lm + 16 * (2 * (lq & 1) + (d >> 1))) << 2;
    const bool lowhalf = (lq < 2);

    const unsigned short* kpt = kT
        + ((size_t)b * NPOS + iq * 512 + (w >> 1) * 16 + lm) * CH
        + (w & 1) * 32 + lq * 8;
    const unsigned short* vpt = vbs
        + ((size_t)b * CH + w * 16 + lm) * NPOS + iq * 512 + lq * 8;

    f32x4 acc[2][4] = {};
    s16x8 kst = *(const s16x8*)kpt;
    s16x8 vst = *(const s16x8*)vpt;

    for (int t = 0; t < 16; ++t) {
        const int buf = t & 1;
        *(s16x8*)&kbuf[buf][w * 512 + l * 8] = kst;
        *(s16x8*)&vbuf[buf][w * 512 + l * 8] = vst;
        if (t < 15) {
            kst = *(const s16x8*)(kpt + (t + 1) * 32 * CH);
            vst = *(const s16x8*)(vpt + (t + 1) * 32);
        }
        __syncthreads();

        s16x8 kA[2][2], vA[4];
        #pragma unroll
        for (int s = 0; s < 2; ++s)
            #pragma unroll
            for (int kc = 0; kc < 2; ++kc)
                kA[s][kc] = *(const s16x8*)&kbuf[buf][(s * 2 + kc) * 512 + l * 8];
        #pragma unroll
        for (int cs = 0; cs < 4; ++cs)
            vA[cs] = *(const s16x8*)&vbuf[buf][cs * 512 + l * 8];

        f32x4 rl0 = *(const f32x4*)&rls[t * 32 + lq * 4];
        f32x4 rl1 = *(const f32x4*)&rls[t * 32 + 16 + lq * 4];

        #pragma unroll
        for (int js = 0; js < 2; ++js) {
            f32x4 s0 = {0,0,0,0}, s1 = {0,0,0,0};
            s0 = __builtin_amdgcn_mfma_f32_16x16x32_bf16(kA[0][0], qb[js][0], s0, 0,0,0);
            s0 = __builtin_amdgcn_mfma_f32_16x16x32_bf16(kA[0][1], qb[js][1], s0, 0,0,0);
            s1 = __builtin_amdgcn_mfma_f32_16x16x32_bf16(kA[1][0], qb[js][0], s1, 0,0,0);
            s1 = __builtin_amdgcn_mfma_f32_16x16x32_bf16(kA[1][1], qb[js][1], s1, 0,0,0);

            unsigned int P0[2], P1[2];
            P0[0] = pk_fast(__expf(s0[0]) * rl0[0], __expf(s0[1]) * rl0[1]);
            P0[1] = pk_fast(__expf(s0[2]) * rl0[2], __expf(s0[3]) * rl0[3]);
            P1[0] = pk_fast(__expf(s1[0]) * rl1[0], __expf(s1[1]) * rl1[1]);
            P1[1] = pk_fast(__expf(s1[2]) * rl1[2], __expf(s1[3]) * rl1[3]);

            union { unsigned int u[4]; s16x8 v; } B;
            #pragma unroll
            for (int d = 0; d < 4; ++d) {
                int t0 = __builtin_amdgcn_ds_bpermute(addr[d], (int)P0[d & 1]);
                int t1 = __builtin_amdgcn_ds_bpermute(addr[d], (int)P1[d & 1]);
                B.u[d] = lowhalf ? (unsigned int)t0 : (unsigned int)t1;
            }
            #pragma unroll
            for (int cs = 0; cs < 4; ++cs)
                acc[js][cs] = __builtin_amdgcn_mfma_f32_16x16x32_bf16(
                    vA[cs], B.v, acc[js][cs], 0,0,0);
        }
    }

    unsigned short* Up = U + ((size_t)iq * NB + b) * NPOS * CH;
    #pragma unroll
    for (int js = 0; js < 2; ++js)
        #pragma unroll
        for (int cs = 0; cs < 4; ++cs) {
            uint2 st = make_uint2(pk_rne(acc[js][cs][0], acc[js][cs][1]),
                                  pk_rne(acc[js][cs][2], acc[js][cs][3]));
            *(uint2*)&Up[(size_t)(j0 + w * 32 + js * 16 + lm) * CH
                         + cs * 16 + lq * 4] = st;
        }
}

// ---------------------------------------------------------------------------
// Kernel 5: post projection + residual.  B = sum of 8 bf16 U partials
// (fp32 accumulate), A = pre-packed Wpost bf16, + x residual.
// Block = (b, 32-pos); 256 blocks.
// ---------------------------------------------------------------------------
__global__ __launch_bounds__(256) void post_kernel(
    const float* __restrict__ x, const unsigned short* __restrict__ Wb,
    const unsigned short* __restrict__ U, float* __restrict__ out)
{
    const int b  = blockIdx.y;
    const int p0 = blockIdx.x * 32;
    const int tid = threadIdx.x;
    const int w = tid >> 6, l = tid & 63, lm = l & 15, lq = l >> 4;
    const int psub = (w & 1) * 16, ohalf = w >> 1;
    const int p = p0 + psub + lm;
    const size_t PS = (size_t)NB * NPOS * CH;

    const unsigned short* u = U + ((size_t)b * NPOS + p) * CH;
    const unsigned short* Wpb = Wb + 3 * 8192;
    s16x8 Bf[2];
    #pragma unroll
    for (int ck = 0; ck < 2; ++ck) {
        float sv[8] = {};
        #pragma unroll
        for (int qq = 0; qq < 8; ++qq) {
            union { s16x8 v; unsigned short us[8]; } uu;
            uu.v = *(const s16x8*)(u + (size_t)qq * PS + ck * 32 + lq * 8);
            #pragma unroll
            for (int j = 0; j < 8; ++j) sv[j] += bf2f(uu.us[j]);
        }
        union { unsigned int u[4]; s16x8 v; } cb;
        #pragma unroll
        for (int j = 0; j < 4; ++j) cb.u[j] = pk_rne(sv[2*j], sv[2*j+1]);
        Bf[ck] = cb.v;
    }

    #pragma unroll
    for (int ot = 0; ot < 4; ++ot) {
        const int o0 = (ohalf * 4 + ot) * 16;
        f32x4 acc = {0.f, 0.f, 0.f, 0.f};
        #pragma unroll
        for (int ck = 0; ck < 2; ++ck) {
            s16x8 aW = *(const s16x8*)&Wpb[(o0 + lm) * CH + ck * 32 + lq * 8];
            acc = __builtin_amdgcn_mfma_f32_16x16x32_bf16(aW, Bf[ck], acc, 0,0,0);
        }
        #pragma unroll
        for (int r = 0; r < 4; ++r) {
            size_t gi = ((size_t)b * CIN + o0 + lq * 4 + r) * NPOS + p;
            out[gi] = x[gi] + acc[r];
        }
    }
}

extern "C" void kernel_launch(void* const* d_in, const int* in_sizes, int n_in,
                              void* d_out, int out_size, void* d_ws, size_t ws_size,
                              hipStream_t stream) {
    const float* x     = (const float*)d_in[0];
    const float* Wq    = (const float*)d_in[1];
    const float* Wk    = (const float*)d_in[2];
    const float* Wv    = (const float*)d_in[3];
    const float* Wpost = (const float*)d_in[4];
    float* out = (float*)d_out;

    // ws: kT(1MB) qT(1MB) vbs(1MB) Wb(64KB) lpart(256KB) gl(32KB) U(8MB bf16)
    unsigned short* kT  = (unsigned short*)d_ws;
    unsigned short* qT  = kT + (size_t)NB * NPOS * CH;
    unsigned short* vbs = qT + (size_t)NB * NPOS * CH;
    unsigned short* Wb  = vbs + (size_t)NB * NPOS * CH;
    float* lpart = (float*)(Wb + 4 * 8192);
    float* gl    = lpart + (size_t)8 * NB * NPOS;
    unsigned short* U = (unsigned short*)(gl + (size_t)NB * NPOS);

    packw_kernel<<<dim3(32), 256, 0, stream>>>(Wq, Wk, Wv, Wpost, Wb);
    qkv_kernel  <<<dim3(NPOS / 16, NB), 256, 0, stream>>>(x, Wb, kT, qT, vbs);
    stats_kernel<<<dim3(NPOS / 64, 8, NB), 256, 0, stream>>>(kT, qT, lpart);
    gl_kernel   <<<dim3(8), 256, 0, stream>>>(lpart, gl);
    agg_kernel  <<<dim3(NPOS / 128, 8, NB), 256, 0, stream>>>(kT, qT, vbs, gl, U);
    post_kernel <<<dim3(NPOS / 32, NB), 256, 0, stream>>>(x, Wb, U, out);
}